// Round 7
// baseline (214.808 us; speedup 1.0000x reference)
//
#include <hip/hip_runtime.h>
#include <stdint.h>

#define NB1     64u           // coarse buckets (hash bits 26..31)
#define CAP1    69632u        // per-coarse capacity (mean 65536, +16 sigma)
#define NB2     4096u         // fine buckets (hash bits 20..31)
#define CAPB    1536u         // per-fine capacity (mean 1024, +16 sigma)
#define LCAP    2048u         // LDS hash-table capacity (per table)
#define LMASK   (LCAP - 1u)
#define EMPTY   0xFFFFFFFFu
#define MAXIT   (CAPB / 256u) // 6 records per thread in count kernel
#define CHUNK   4096u         // records per scatter block
#define STHR    512u          // scatter block size
#define NSLICE  17u           // slices per coarse bucket in scatter2
#define NPB     128u          // position buckets for output pairs
#define POSB_SH 15u
#define POSB    (1u << POSB_SH)   // 32768 positions per bucket (exact for n=2^22)

__device__ __forceinline__ uint32_t hash32(uint32_t x) {
    x *= 2654435761u;
    x ^= x >> 16;
    x *= 0x85ebca6bu;
    x ^= x >> 13;
    return x;
}

__device__ __forceinline__ void make_keys(const int* __restrict__ tok, int i,
                                          uint32_t& ckey, uint32_t& t0) {
    t0 = (uint32_t)tok[i];
    uint32_t t1 = (i >= 1) ? (uint32_t)tok[i - 1] : 0u;
    uint32_t t2 = (i >= 2) ? (uint32_t)tok[i - 2] : 0u;
    uint32_t t3 = (i >= 3) ? (uint32_t)tok[i - 3] : 0u;
    ckey = (t3 << 20) | (t2 << 10) | t1;   // 30-bit context key
}

// Record: u64 = (pkey40 << 22) | pos22 ; ckey = rec >> 32. Weight in wrec[].

// 64-entry exclusive scan + global reservation, done by lanes 0..63.
__device__ __forceinline__ void scan_reserve(uint32_t* hist, uint32_t* cur,
                                             uint32_t* scanb, uint32_t* gbase,
                                             uint32_t* gt, uint32_t gstride_id) {
    if (threadIdx.x < 64u) {
        uint32_t h = hist[threadIdx.x];
        uint32_t inc = h;
        #pragma unroll
        for (int d = 1; d < 64; d <<= 1) {
            uint32_t o = __shfl_up(inc, d, 64);
            if ((int)threadIdx.x >= d) inc += o;
        }
        uint32_t ex = inc - h;
        scanb[threadIdx.x] = ex;
        cur[threadIdx.x] = ex;
        gbase[threadIdx.x] = h ? atomicAdd(&gt[gstride_id + threadIdx.x], h) : 0u;
    }
}

// Pass 1: partition into 64 coarse buckets with LDS-sorted coalesced flush.
__global__ void __launch_bounds__(STHR) scatter1_kernel(
        const int* __restrict__ tok, const float* __restrict__ w,
        unsigned long long* __restrict__ rec1, float* __restrict__ wrec1,
        uint32_t* __restrict__ gt1, int n) {
    __shared__ uint32_t hist[NB1], cur[NB1], scanb[NB1], gbase[NB1];
    __shared__ unsigned long long srec[CHUNK];
    __shared__ float sw[CHUNK];

    int start = blockIdx.x * (int)CHUNK;
    int end = start + (int)CHUNK; if (end > n) end = n;
    int cnt = end - start;

    if (threadIdx.x < NB1) hist[threadIdx.x] = 0;
    __syncthreads();

    for (int i = start + threadIdx.x; i < end; i += STHR) {
        uint32_t ckey, t0;
        make_keys(tok, i, ckey, t0);
        atomicAdd(&hist[hash32(ckey) >> 26], 1u);
    }
    __syncthreads();

    scan_reserve(hist, cur, scanb, gbase, gt1, 0u);
    __syncthreads();

    for (int i = start + threadIdx.x; i < end; i += STHR) {
        uint32_t ckey, t0;
        make_keys(tok, i, ckey, t0);
        uint32_t b = hash32(ckey) >> 26;
        uint64_t pkey = (((uint64_t)ckey) << 10) | (uint64_t)t0;
        uint32_t r = atomicAdd(&cur[b], 1u);
        srec[r] = (pkey << 22) | (uint64_t)(uint32_t)i;
        sw[r] = w[i];
    }
    __syncthreads();

    for (uint32_t j = threadIdx.x; j < (uint32_t)cnt; j += STHR) {
        unsigned long long e = srec[j];
        uint32_t b = hash32((uint32_t)(e >> 32)) >> 26;
        uint32_t loc = gbase[b] + (j - scanb[b]);
        if (loc < CAP1) {
            size_t dst = (size_t)b * CAP1 + loc;
            rec1[dst] = e;
            wrec1[dst] = sw[j];
        }
    }
}

// Pass 2: refine each coarse bucket into 64 fine buckets, same staging trick.
__global__ void __launch_bounds__(STHR) scatter2_kernel(
        const unsigned long long* __restrict__ rec1,
        const float* __restrict__ wrec1,
        const uint32_t* __restrict__ gt1,
        unsigned long long* __restrict__ rec2, float* __restrict__ wrec2,
        uint32_t* __restrict__ gt2) {
    __shared__ uint32_t hist[64], cur[64], scanb[64], gbase[64];
    __shared__ unsigned long long srec[CHUNK];
    __shared__ float sw[CHUNK];

    uint32_t c = blockIdx.x / NSLICE;
    uint32_t sl = blockIdx.x % NSLICE;
    uint32_t m = gt1[c]; if (m > CAP1) m = CAP1;
    uint32_t lo = sl * CHUNK;
    if (lo >= m) return;
    uint32_t hi = lo + CHUNK; if (hi > m) hi = m;
    uint32_t cnt = hi - lo;
    size_t srcbase = (size_t)c * CAP1;

    if (threadIdx.x < 64u) hist[threadIdx.x] = 0;
    __syncthreads();

    for (uint32_t r = lo + threadIdx.x; r < hi; r += STHR) {
        uint32_t ckey = (uint32_t)(rec1[srcbase + r] >> 32);
        atomicAdd(&hist[(hash32(ckey) >> 20) & 63u], 1u);
    }
    __syncthreads();

    scan_reserve(hist, cur, scanb, gbase, gt2, c * 64u);
    __syncthreads();

    for (uint32_t r = lo + threadIdx.x; r < hi; r += STHR) {
        unsigned long long e = rec1[srcbase + r];
        uint32_t f = (hash32((uint32_t)(e >> 32)) >> 20) & 63u;
        uint32_t rk = atomicAdd(&cur[f], 1u);
        srec[rk] = e;
        sw[rk] = wrec1[srcbase + r];
    }
    __syncthreads();

    for (uint32_t j = threadIdx.x; j < cnt; j += STHR) {
        unsigned long long e = srec[j];
        uint32_t f = (hash32((uint32_t)(e >> 32)) >> 20) & 63u;
        uint32_t loc = gbase[f] + (j - scanb[f]);
        if (loc < CAPB) {
            size_t dst = (size_t)(c * 64u + f) * CAPB + loc;
            rec2[dst] = e;
            wrec2[dst] = sw[j];
        }
    }
}

// One block per fine bucket: count in LDS, compute val = pc/(cc+1) per record,
// then multisplit (pos,val) pairs by pos-bucket with coalesced flush.
__global__ void __launch_bounds__(256) count_emit_kernel(
        const unsigned long long* __restrict__ rec,
        const float* __restrict__ wrec,
        const uint32_t* __restrict__ gtail,
        unsigned long long* __restrict__ pairs,
        uint32_t* __restrict__ ptail) {
    __shared__ uint32_t ckk[LCAP];  __shared__ float ckc[LCAP];
    __shared__ uint32_t pkk[LCAP];  __shared__ float pkc[LCAP];
    __shared__ unsigned long long spair[CAPB];
    __shared__ uint32_t phist[NPB], pcur[NPB], scanp[NPB], pgb[NPB];

    uint32_t b = blockIdx.x;
    uint32_t m = gtail[b]; if (m > CAPB) m = CAPB;
    uint32_t tid = threadIdx.x;

    for (uint32_t k = tid; k < LCAP; k += 256u) {
        ckk[k] = EMPTY; ckc[k] = 0.0f;
        pkk[k] = EMPTY; pkc[k] = 0.0f;
    }
    if (tid < NPB) phist[tid] = 0;

    // Phase A: front-load all global reads
    unsigned long long ee[MAXIT];
    float wv[MAXIT];
    #pragma unroll
    for (uint32_t it = 0; it < MAXIT; ++it) {
        uint32_t r = tid + it * 256u;
        if (r < m) {
            ee[it] = rec[(size_t)b * CAPB + r];
            wv[it] = wrec[(size_t)b * CAPB + r];
        }
    }
    __syncthreads();

    // Phase B: LDS insert-or-find + accumulate
    uint32_t ss[MAXIT], uu[MAXIT], pp[MAXIT];
    #pragma unroll
    for (uint32_t it = 0; it < MAXIT; ++it) {
        uint32_t r = tid + it * 256u;
        if (r < m) {
            unsigned long long e = ee[it];
            uint32_t pos = (uint32_t)e & 0x3FFFFFu;
            uint64_t pkey = e >> 22;
            uint32_t ckey = (uint32_t)(pkey >> 10);
            uint32_t t0 = (uint32_t)pkey & 1023u;
            float wi = wv[it];

            uint32_t h = hash32(ckey) & LMASK;   // bits 0..10, indep of 20..31
            uint32_t s;
            while (true) {
                uint32_t prev = atomicCAS(&ckk[h], EMPTY, ckey);
                if (prev == EMPTY || prev == ckey) { s = h; break; }
                h = (h + 1u) & LMASK;
            }
            atomicAdd(&ckc[s], wi);

            uint32_t pk2 = (s << 10) | t0;       // 21-bit in-bucket pair key
            uint32_t h2 = hash32(pk2) & LMASK;
            uint32_t u;
            while (true) {
                uint32_t prev = atomicCAS(&pkk[h2], EMPTY, pk2);
                if (prev == EMPTY || prev == pk2) { u = h2; break; }
                h2 = (h2 + 1u) & LMASK;
            }
            atomicAdd(&pkc[u], wi);

            ss[it] = s; uu[it] = u; pp[it] = pos;
        }
    }
    __syncthreads();

    // Phase C: compute val per record, histogram by pos-bucket
    #pragma unroll
    for (uint32_t it = 0; it < MAXIT; ++it) {
        uint32_t r = tid + it * 256u;
        if (r < m) {
            wv[it] = pkc[uu[it]] / (ckc[ss[it]] + 1.0f);   // reuse wv as val
            atomicAdd(&phist[pp[it] >> POSB_SH], 1u);
        }
    }
    __syncthreads();

    // 128-entry exclusive scan (two 64-lane wave scans + fixup) + reservation
    if (tid < NPB) {
        uint32_t h = phist[tid];
        uint32_t inc = h;
        #pragma unroll
        for (int d = 1; d < 64; d <<= 1) {
            uint32_t o = __shfl_up(inc, d, 64);
            if ((int)(tid & 63u) >= d) inc += o;
        }
        scanp[tid] = inc - h;                    // wave-local exclusive
        pgb[tid] = h ? atomicAdd(&ptail[tid], h) : 0u;
    }
    __syncthreads();
    if (tid >= 64u && tid < NPB) scanp[tid] += scanp[63] + phist[63];
    __syncthreads();
    if (tid < NPB) pcur[tid] = scanp[tid];
    __syncthreads();

    // Stage pairs in pos-bucket-sorted order
    #pragma unroll
    for (uint32_t it = 0; it < MAXIT; ++it) {
        uint32_t r = tid + it * 256u;
        if (r < m) {
            uint32_t pos = pp[it];
            unsigned long long pe = ((unsigned long long)pos << 32)
                                  | (unsigned long long)__float_as_uint(wv[it]);
            uint32_t rk = atomicAdd(&pcur[pos >> POSB_SH], 1u);
            spair[rk] = pe;
        }
    }
    __syncthreads();

    // Coalesced flush of pairs
    for (uint32_t j = tid; j < m; j += 256u) {
        unsigned long long e = spair[j];
        uint32_t pb = (uint32_t)(e >> 32) >> POSB_SH;
        uint32_t loc = pgb[pb] + (j - scanp[pb]);
        pairs[((size_t)pb << POSB_SH) + loc] = e;
    }
}

// One block per position bucket: scatter vals into LDS image, coalesced out write.
__global__ void final_out_kernel(const unsigned long long* __restrict__ pairs,
                                 const uint32_t* __restrict__ ptail,
                                 float* __restrict__ out, int n) {
    extern __shared__ float img[];
    uint32_t b = blockIdx.x;
    uint32_t m = ptail[b]; if (m > POSB) m = POSB;
    uint32_t base = b << POSB_SH;

    for (uint32_t j = threadIdx.x; j < POSB; j += blockDim.x) img[j] = 0.0f;
    __syncthreads();

    for (uint32_t j = threadIdx.x; j < m; j += blockDim.x) {
        unsigned long long e = pairs[((size_t)b << POSB_SH) + j];
        img[(uint32_t)(e >> 32) & (POSB - 1u)] = __uint_as_float((uint32_t)e);
    }
    __syncthreads();

    for (uint32_t j = threadIdx.x; j < POSB; j += blockDim.x) {
        uint32_t i = base + j;
        if (i < (uint32_t)n) out[i] = img[j];
    }
}

extern "C" void kernel_launch(void* const* d_in, const int* in_sizes, int n_in,
                              void* d_out, int out_size, void* d_ws, size_t ws_size,
                              hipStream_t stream) {
    const int* tok = (const int*)d_in[0];
    const float* w = (const float*)d_in[1];
    float* out = (float*)d_out;
    const int n = in_sizes[0];

    char* ws = (char*)d_ws;
    size_t n1 = (size_t)NB1 * CAP1;          // 4,456,448 coarse slots
    size_t n2 = (size_t)NB2 * CAPB;          // 6,291,456 fine slots
    unsigned long long* rec1 = (unsigned long long*)ws;             // 35.7 MB
    float* wrec1 = (float*)(ws + n1 * 8);                           // 17.8 MB
    unsigned long long* rec2 = (unsigned long long*)(ws + n1 * 12); // 50.3 MB
    float* wrec2 = (float*)(ws + n1 * 12 + n2 * 8);                 // 25.2 MB
    uint32_t* gt1 = (uint32_t*)(ws + n1 * 12 + n2 * 12);            // 64 u32
    uint32_t* gt2 = gt1 + NB1;                                      // 4096 u32
    uint32_t* ptail = gt2 + NB2;                                    // 128 u32
    // pairs overlay rec1 (dead after scatter2): 128*32768*8 = 33.6 MB <= 35.7 MB
    unsigned long long* pairs = (unsigned long long*)ws;

    hipMemsetAsync(gt1, 0, (NB1 + NB2 + NPB) * sizeof(uint32_t), stream);

    int g1 = (n + (int)CHUNK - 1) / (int)CHUNK;       // 1024 for n=2^22
    scatter1_kernel<<<g1, STHR, 0, stream>>>(tok, w, rec1, wrec1, gt1, n);
    scatter2_kernel<<<NB1 * NSLICE, STHR, 0, stream>>>(rec1, wrec1, gt1, rec2, wrec2, gt2);
    count_emit_kernel<<<NB2, 256, 0, stream>>>(rec2, wrec2, gt2, pairs, ptail);
    final_out_kernel<<<NPB, 1024, POSB * sizeof(float), stream>>>(pairs, ptail, out, n);
}

// Round 8
// 176.104 us; speedup vs baseline: 1.2198x; 1.2198x over previous
//
#include <hip/hip_runtime.h>
#include <stdint.h>

#define NB1     64u            // coarse buckets (hash bits 26..31)
#define CAP1    69632u         // per-coarse capacity (mean 65536, +16 sigma)
#define NB2     4096u          // fine buckets (hash bits 20..31)
#define CAPB    1536u          // per-fine capacity (mean 1024, +16 sigma)
#define LCAP    2048u          // LDS hash-table capacity (per table)
#define LMASK   (LCAP - 1u)
#define EMPTY64 0xFFFFFFFFFFFFFFFFULL
#define CHUNK   4096u          // records per scatter block
#define STHR    512u           // scatter block size
#define SIT     (CHUNK / STHR) // 8 records per thread in scatters
#define NSLICE  17u            // slices per coarse bucket in scatter2
#define CTHR    512u           // count_emit block size
#define MAXIT   (CAPB / CTHR)  // 3 records per thread in count kernel
#define NPB     128u           // position buckets for output pairs
#define POSB_SH 15u
#define POSB    (1u << POSB_SH)

__device__ __forceinline__ uint32_t hash32(uint32_t x) {
    x *= 2654435761u;
    x ^= x >> 16;
    x *= 0x85ebca6bu;
    x ^= x >> 13;
    return x;
}

__device__ __forceinline__ void make_keys(const int* __restrict__ tok, int i,
                                          uint32_t& ckey, uint32_t& t0) {
    t0 = (uint32_t)tok[i];
    uint32_t t1 = (i >= 1) ? (uint32_t)tok[i - 1] : 0u;
    uint32_t t2 = (i >= 2) ? (uint32_t)tok[i - 2] : 0u;
    uint32_t t3 = (i >= 3) ? (uint32_t)tok[i - 3] : 0u;
    ckey = (t3 << 20) | (t2 << 10) | t1;   // 30-bit context key
}

// Record: u64 = (pkey40 << 22) | pos22 ; ckey = rec >> 32. Weight in wrec[].

// 64-entry exclusive scan + global reservation (lanes 0..63).
__device__ __forceinline__ void scan_reserve(uint32_t* hist, uint32_t* cur,
                                             uint32_t* scanb, uint32_t* gbase,
                                             uint32_t* gt, uint32_t gstride_id) {
    if (threadIdx.x < 64u) {
        uint32_t h = hist[threadIdx.x];
        uint32_t inc = h;
        #pragma unroll
        for (int d = 1; d < 64; d <<= 1) {
            uint32_t o = __shfl_up(inc, d, 64);
            if ((int)threadIdx.x >= d) inc += o;
        }
        uint32_t ex = inc - h;
        scanb[threadIdx.x] = ex;
        cur[threadIdx.x] = ex;
        gbase[threadIdx.x] = h ? atomicAdd(&gt[gstride_id + threadIdx.x], h) : 0u;
    }
}

// Fused insert-or-accumulate into a u64 {key32|count_f32} LDS table region.
// Returns slot index. One CAS in the common (new-key) case.
__device__ __forceinline__ uint32_t lds_upsert(unsigned long long* tab,
                                               uint32_t key, float wi,
                                               uint32_t h) {
    unsigned long long want = ((unsigned long long)key << 32)
                            | (unsigned long long)__float_as_uint(wi);
    while (true) {
        unsigned long long old = atomicCAS(&tab[h], EMPTY64, want);
        if (old == EMPTY64) return h;
        if ((uint32_t)(old >> 32) == key) {          // rare duplicate: add
            while (true) {
                unsigned long long nw = (old & 0xFFFFFFFF00000000ULL)
                    | (unsigned long long)__float_as_uint(
                          __uint_as_float((uint32_t)old) + wi);
                unsigned long long p = atomicCAS(&tab[h], old, nw);
                if (p == old) return h;
                old = p;
            }
        }
        h = (h + 1u) & LMASK;
    }
}

// Pass 1: partition into 64 coarse buckets, register-carried single-read.
__global__ void __launch_bounds__(STHR) scatter1_kernel(
        const int* __restrict__ tok, const float* __restrict__ w,
        unsigned long long* __restrict__ rec1, float* __restrict__ wrec1,
        uint32_t* __restrict__ gt1, int n) {
    __shared__ uint32_t hist[NB1], cur[NB1], scanb[NB1], gbase[NB1];
    __shared__ unsigned long long srec[CHUNK];
    __shared__ float sw[CHUNK];

    int start = blockIdx.x * (int)CHUNK;
    int end = start + (int)CHUNK; if (end > n) end = n;
    int cnt = end - start;

    if (threadIdx.x < NB1) hist[threadIdx.x] = 0;
    __syncthreads();

    unsigned long long rr[SIT]; float ww[SIT]; uint32_t bb[SIT];
    #pragma unroll
    for (uint32_t it = 0; it < SIT; ++it) {
        int i = start + (int)threadIdx.x + (int)(it * STHR);
        bb[it] = 0xFFFFFFFFu;
        if (i < end) {
            uint32_t ckey, t0;
            make_keys(tok, i, ckey, t0);
            uint64_t pkey = (((uint64_t)ckey) << 10) | (uint64_t)t0;
            rr[it] = (pkey << 22) | (uint64_t)(uint32_t)i;
            ww[it] = w[i];
            bb[it] = hash32(ckey) >> 26;
            atomicAdd(&hist[bb[it]], 1u);
        }
    }
    __syncthreads();

    scan_reserve(hist, cur, scanb, gbase, gt1, 0u);
    __syncthreads();

    #pragma unroll
    for (uint32_t it = 0; it < SIT; ++it) {
        if (bb[it] != 0xFFFFFFFFu) {
            uint32_t r = atomicAdd(&cur[bb[it]], 1u);
            srec[r] = rr[it];
            sw[r] = ww[it];
        }
    }
    __syncthreads();

    for (uint32_t j = threadIdx.x; j < (uint32_t)cnt; j += STHR) {
        unsigned long long e = srec[j];
        uint32_t b = hash32((uint32_t)(e >> 32)) >> 26;
        uint32_t loc = gbase[b] + (j - scanb[b]);
        if (loc < CAP1) {
            size_t dst = (size_t)b * CAP1 + loc;
            rec1[dst] = e;
            wrec1[dst] = sw[j];
        }
    }
}

// Pass 2: refine each coarse bucket into 64 fine buckets, register-carried.
__global__ void __launch_bounds__(STHR) scatter2_kernel(
        const unsigned long long* __restrict__ rec1,
        const float* __restrict__ wrec1,
        const uint32_t* __restrict__ gt1,
        unsigned long long* __restrict__ rec2, float* __restrict__ wrec2,
        uint32_t* __restrict__ gt2) {
    __shared__ uint32_t hist[64], cur[64], scanb[64], gbase[64];
    __shared__ unsigned long long srec[CHUNK];
    __shared__ float sw[CHUNK];

    uint32_t c = blockIdx.x / NSLICE;
    uint32_t sl = blockIdx.x % NSLICE;
    uint32_t m = gt1[c]; if (m > CAP1) m = CAP1;
    uint32_t lo = sl * CHUNK;
    if (lo >= m) return;
    uint32_t hi = lo + CHUNK; if (hi > m) hi = m;
    uint32_t cnt = hi - lo;
    size_t srcbase = (size_t)c * CAP1;

    if (threadIdx.x < 64u) hist[threadIdx.x] = 0;
    __syncthreads();

    unsigned long long rr[SIT]; float ww[SIT]; uint32_t ff[SIT];
    #pragma unroll
    for (uint32_t it = 0; it < SIT; ++it) {
        uint32_t r = lo + threadIdx.x + it * STHR;
        ff[it] = 0xFFFFFFFFu;
        if (r < hi) {
            rr[it] = rec1[srcbase + r];
            ww[it] = wrec1[srcbase + r];
            ff[it] = (hash32((uint32_t)(rr[it] >> 32)) >> 20) & 63u;
            atomicAdd(&hist[ff[it]], 1u);
        }
    }
    __syncthreads();

    scan_reserve(hist, cur, scanb, gbase, gt2, c * 64u);
    __syncthreads();

    #pragma unroll
    for (uint32_t it = 0; it < SIT; ++it) {
        if (ff[it] != 0xFFFFFFFFu) {
            uint32_t rk = atomicAdd(&cur[ff[it]], 1u);
            srec[rk] = rr[it];
            sw[rk] = ww[it];
        }
    }
    __syncthreads();

    for (uint32_t j = threadIdx.x; j < cnt; j += STHR) {
        unsigned long long e = srec[j];
        uint32_t f = (hash32((uint32_t)(e >> 32)) >> 20) & 63u;
        uint32_t loc = gbase[f] + (j - scanb[f]);
        if (loc < CAPB) {
            size_t dst = (size_t)(c * 64u + f) * CAPB + loc;
            rec2[dst] = e;
            wrec2[dst] = sw[j];
        }
    }
}

// One block per fine bucket: fused-u64 LDS counting, then multisplit (pos,val)
// pairs by pos-bucket. spair overlays the dead cke table half.
__global__ void __launch_bounds__(CTHR) count_emit_kernel(
        const unsigned long long* __restrict__ rec,
        const float* __restrict__ wrec,
        const uint32_t* __restrict__ gtail,
        unsigned long long* __restrict__ pairs,
        uint32_t* __restrict__ ptail) {
    __shared__ unsigned long long tbl[2u * LCAP];   // [0,LCAP)=cke, [LCAP,2LCAP)=pke
    __shared__ uint32_t phist[NPB], pcur[NPB], scanp[NPB], pgb[NPB];

    uint32_t b = blockIdx.x;
    uint32_t m = gtail[b]; if (m > CAPB) m = CAPB;
    uint32_t tid = threadIdx.x;

    for (uint32_t k = tid; k < 2u * LCAP; k += CTHR) tbl[k] = EMPTY64;
    if (tid < NPB) phist[tid] = 0;

    // Phase A: front-load all global reads into registers
    unsigned long long ee[MAXIT];
    float wv[MAXIT];
    #pragma unroll
    for (uint32_t it = 0; it < MAXIT; ++it) {
        uint32_t r = tid + it * CTHR;
        if (r < m) {
            ee[it] = rec[(size_t)b * CAPB + r];
            wv[it] = wrec[(size_t)b * CAPB + r];
        }
    }
    __syncthreads();

    // Phase B: fused insert-or-accumulate, + pos-bucket histogram
    uint32_t ss[MAXIT], uu[MAXIT], pp[MAXIT];
    #pragma unroll
    for (uint32_t it = 0; it < MAXIT; ++it) {
        uint32_t r = tid + it * CTHR;
        pp[it] = 0xFFFFFFFFu;
        if (r < m) {
            unsigned long long e = ee[it];
            uint32_t pos = (uint32_t)e & 0x3FFFFFu;
            uint64_t pkey = e >> 22;
            uint32_t ckey = (uint32_t)(pkey >> 10);
            uint32_t t0 = (uint32_t)pkey & 1023u;
            float wi = wv[it];

            uint32_t s = lds_upsert(tbl, ckey, wi, hash32(ckey) & LMASK);
            uint32_t pk2 = (s << 10) | t0;          // 21-bit in-bucket pair key
            uint32_t u = lds_upsert(tbl + LCAP, pk2, wi, hash32(pk2) & LMASK);

            ss[it] = s; uu[it] = u; pp[it] = pos;
            atomicAdd(&phist[pos >> POSB_SH], 1u);
        }
    }
    __syncthreads();

    // Phase C: read final counts -> val ; then wave-scan phist (tid<128)
    #pragma unroll
    for (uint32_t it = 0; it < MAXIT; ++it) {
        if (pp[it] != 0xFFFFFFFFu) {
            float cc = __uint_as_float((uint32_t)tbl[ss[it]]);
            float pc = __uint_as_float((uint32_t)tbl[LCAP + uu[it]]);
            wv[it] = pc / (cc + 1.0f);              // reuse wv as val
        }
    }
    if (tid < NPB) {
        uint32_t h = phist[tid];
        uint32_t inc = h;
        #pragma unroll
        for (int d = 1; d < 64; d <<= 1) {
            uint32_t o = __shfl_up(inc, d, 64);
            if ((int)(tid & 63u) >= d) inc += o;
        }
        scanp[tid] = inc - h;                        // wave-local exclusive
        pgb[tid] = h ? atomicAdd(&ptail[tid], h) : 0u;
    }
    __syncthreads();
    if (tid >= 64u && tid < NPB) scanp[tid] += scanp[63] + phist[63];
    __syncthreads();
    if (tid < NPB) pcur[tid] = scanp[tid];
    __syncthreads();

    // Stage pairs (overlay cke region: m <= CAPB <= LCAP, tables dead now)
    unsigned long long* spair = tbl;
    #pragma unroll
    for (uint32_t it = 0; it < MAXIT; ++it) {
        if (pp[it] != 0xFFFFFFFFu) {
            uint32_t pos = pp[it];
            unsigned long long pe = ((unsigned long long)pos << 32)
                                  | (unsigned long long)__float_as_uint(wv[it]);
            uint32_t rk = atomicAdd(&pcur[pos >> POSB_SH], 1u);
            spair[rk] = pe;
        }
    }
    __syncthreads();

    // Coalesced flush of pairs
    for (uint32_t j = tid; j < m; j += CTHR) {
        unsigned long long e = spair[j];
        uint32_t pb = (uint32_t)(e >> 32) >> POSB_SH;
        uint32_t loc = pgb[pb] + (j - scanp[pb]);
        pairs[((size_t)pb << POSB_SH) + loc] = e;
    }
}

// One block per position bucket: scatter vals into LDS image, coalesced write.
__global__ void final_out_kernel(const unsigned long long* __restrict__ pairs,
                                 const uint32_t* __restrict__ ptail,
                                 float* __restrict__ out, int n) {
    extern __shared__ float img[];
    uint32_t b = blockIdx.x;
    uint32_t m = ptail[b]; if (m > POSB) m = POSB;
    uint32_t base = b << POSB_SH;

    for (uint32_t j = threadIdx.x; j < POSB; j += blockDim.x) img[j] = 0.0f;
    __syncthreads();

    for (uint32_t j = threadIdx.x; j < m; j += blockDim.x) {
        unsigned long long e = pairs[((size_t)b << POSB_SH) + j];
        img[(uint32_t)(e >> 32) & (POSB - 1u)] = __uint_as_float((uint32_t)e);
    }
    __syncthreads();

    for (uint32_t j = threadIdx.x; j < POSB; j += blockDim.x) {
        uint32_t i = base + j;
        if (i < (uint32_t)n) out[i] = img[j];
    }
}

extern "C" void kernel_launch(void* const* d_in, const int* in_sizes, int n_in,
                              void* d_out, int out_size, void* d_ws, size_t ws_size,
                              hipStream_t stream) {
    const int* tok = (const int*)d_in[0];
    const float* w = (const float*)d_in[1];
    float* out = (float*)d_out;
    const int n = in_sizes[0];

    char* ws = (char*)d_ws;
    size_t n1 = (size_t)NB1 * CAP1;          // 4,456,448 coarse slots
    size_t n2 = (size_t)NB2 * CAPB;          // 6,291,456 fine slots
    unsigned long long* rec1 = (unsigned long long*)ws;             // 35.7 MB
    float* wrec1 = (float*)(ws + n1 * 8);                           // 17.8 MB
    unsigned long long* rec2 = (unsigned long long*)(ws + n1 * 12); // 50.3 MB
    float* wrec2 = (float*)(ws + n1 * 12 + n2 * 8);                 // 25.2 MB
    uint32_t* gt1 = (uint32_t*)(ws + n1 * 12 + n2 * 12);            // 64 u32
    uint32_t* gt2 = gt1 + NB1;                                      // 4096 u32
    uint32_t* ptail = gt2 + NB2;                                    // 128 u32
    // pairs overlay rec1 (dead after scatter2): 128*32768*8 = 33.6 MB <= 35.7 MB
    unsigned long long* pairs = (unsigned long long*)ws;

    hipMemsetAsync(gt1, 0, (NB1 + NB2 + NPB) * sizeof(uint32_t), stream);

    int g1 = (n + (int)CHUNK - 1) / (int)CHUNK;       // 1024 for n=2^22
    scatter1_kernel<<<g1, STHR, 0, stream>>>(tok, w, rec1, wrec1, gt1, n);
    scatter2_kernel<<<NB1 * NSLICE, STHR, 0, stream>>>(rec1, wrec1, gt1, rec2, wrec2, gt2);
    count_emit_kernel<<<NB2, CTHR, 0, stream>>>(rec2, wrec2, gt2, pairs, ptail);
    final_out_kernel<<<NPB, 1024, POSB * sizeof(float), stream>>>(pairs, ptail, out, n);
}